// Round 3
// baseline (165.537 us; speedup 1.0000x reference)
//
#include <hip/hip_runtime.h>
#include <hip/hip_bf16.h>

#define B_  2
#define S_  2048
#define D_  1024
#define H_  16
#define DK_ 64
#define M_  (B_ * S_)   // 4096

typedef short short8 __attribute__((ext_vector_type(8)));
typedef float float4v __attribute__((ext_vector_type(4)));

// log2(e)/8 : folded into Q at projection so attention exp is a bare v_exp_f32
#define QSCALE 0.18033688011112042f

static __device__ __forceinline__ ushort f32_to_bf16bits(float f) {
    union { __hip_bfloat16 h; ushort u; } cv;
    cv.h = __float2bfloat16(f);
    return cv.u;
}

// async global->LDS, 16B per lane (lands at wave-uniform base + lane*16)
static __device__ __forceinline__ void glds16(const ushort* g, ushort* l) {
    __builtin_amdgcn_global_load_lds(
        (const __attribute__((address_space(1))) unsigned int*)g,
        (__attribute__((address_space(3))) unsigned int*)l, 16, 0, 0);
}

// ---------------------------------------------------------------------------
// prep: z in [0,3) -> transpose+convert W_z[k][n] fp32 -> Wt[n][k] bf16
//       z in [3,11) -> convert X fp32 -> bf16
// ---------------------------------------------------------------------------
__global__ __launch_bounds__(256) void prep(
    const float* __restrict__ X, const float* __restrict__ W0,
    const float* __restrict__ W1, const float* __restrict__ W2,
    ushort* __restrict__ Xb, ushort* __restrict__ Wt)
{
    const int z = blockIdx.z;
    const int t = threadIdx.x;

    if (z >= 3) {   // convert X
        const int blk = (z - 3) * 256 + blockIdx.y * 16 + blockIdx.x;
        const int i = blk * 2048 + t * 8;
        float4v a = *(const float4v*)(X + i);
        float4v b = *(const float4v*)(X + i + 4);
        short8 o;
        o[0] = (short)f32_to_bf16bits(a[0]); o[1] = (short)f32_to_bf16bits(a[1]);
        o[2] = (short)f32_to_bf16bits(a[2]); o[3] = (short)f32_to_bf16bits(a[3]);
        o[4] = (short)f32_to_bf16bits(b[0]); o[5] = (short)f32_to_bf16bits(b[1]);
        o[6] = (short)f32_to_bf16bits(b[2]); o[7] = (short)f32_to_bf16bits(b[3]);
        *(short8*)(Xb + i) = o;
        return;
    }

    const float* W = (z == 0) ? W0 : ((z == 1) ? W1 : W2);
    ushort* out = Wt + (size_t)z * D_ * D_;

    __shared__ ushort tile[64 * 72];
    int n0 = blockIdx.x * 64, k0 = blockIdx.y * 64;
    int r = t >> 3, g = t & 7;

    #pragma unroll
    for (int p = 0; p < 2; ++p) {
        int rr = r + p * 32;
        const float* src = W + (size_t)(k0 + rr) * D_ + n0 + g * 8;
        float4v a = *(const float4v*)src;
        float4v b = *(const float4v*)(src + 4);
        short8 o;
        o[0] = (short)f32_to_bf16bits(a[0]); o[1] = (short)f32_to_bf16bits(a[1]);
        o[2] = (short)f32_to_bf16bits(a[2]); o[3] = (short)f32_to_bf16bits(a[3]);
        o[4] = (short)f32_to_bf16bits(b[0]); o[5] = (short)f32_to_bf16bits(b[1]);
        o[6] = (short)f32_to_bf16bits(b[2]); o[7] = (short)f32_to_bf16bits(b[3]);
        *(short8*)&tile[rr * 72 + g * 8] = o;
    }
    __syncthreads();
    #pragma unroll
    for (int p = 0; p < 2; ++p) {
        int rr = r + p * 32;
        short8 v;
        #pragma unroll
        for (int i = 0; i < 8; ++i)
            v[i] = (short)tile[(g * 8 + i) * 72 + rr];
        *(short8*)(out + (size_t)(n0 + rr) * D_ + k0 + g * 8) = v;
    }
}

// ---------------------------------------------------------------------------
// FUSED-z QKV projection: one block = (m-tile 64, n-tile 128) computing q, k
// AND v.  A staged once, 48 MFMA per barrier.  56 KB LDS = 2 blocks/CU.
// k/v work skipped (block-uniform) when this m-tile is beyond length[b].
// z==0 (Q) epilogue folds score-scale*log2(e) into the values.
// ---------------------------------------------------------------------------
__global__ __launch_bounds__(256, 2) void proj_gemm(
    const ushort* __restrict__ X,    // [4096][1024] bf16
    const ushort* __restrict__ Wt,   // [3][1024][1024] bf16, n-major
    const float* __restrict__ b0, const float* __restrict__ b1,
    const float* __restrict__ b2,
    const int* __restrict__ length,
    ushort* __restrict__ qkv)        // [3][4M] bf16
{
    const int m0 = blockIdx.x * 64, n0 = blockIdx.y * 128;
    const int bidx = m0 >> 11;
    const int s0 = m0 & (S_ - 1);
    const bool kv = (s0 < length[bidx]);   // block-uniform

    __shared__ __align__(16) ushort As[64 * 64];        //  8 KB
    __shared__ __align__(16) ushort Bs[3][128 * 64];    // 48 KB

    const int t = threadIdx.x;
    const int lane = t & 63, wid = t >> 6;
    const int quad = lane >> 4, l16 = lane & 15;
    const int wr = wid >> 1, wc = wid & 1;

    float4v accq[2][4] = {}, acck[2][4] = {}, accv[2][4] = {};

    for (int kt = 0; kt < 16; ++kt) {
        const int k0 = kt * 64;
        __syncthreads();
        #pragma unroll
        for (int j = 0; j < 2; ++j) {          // A: 512 chunks, 128/wave
            const int cid = wid * 128 + j * 64 + lane;
            const int row = cid >> 3;
            const int cl  = (cid & 7) ^ (row & 7);
            glds16(X + (size_t)(m0 + row) * D_ + k0 + cl * 8, &As[cid * 8]);
        }
        #pragma unroll
        for (int j = 0; j < 4; ++j) {          // B panels: 1024 chunks each
            const int cid = wid * 256 + j * 64 + lane;
            const int row = cid >> 3;
            const int cl  = (cid & 7) ^ (row & 7);
            const size_t off = (size_t)(n0 + row) * D_ + k0 + cl * 8;
            glds16(Wt + off, &Bs[0][cid * 8]);
            if (kv) {
                glds16(Wt + (size_t)D_ * D_ + off,     &Bs[1][cid * 8]);
                glds16(Wt + (size_t)2 * D_ * D_ + off, &Bs[2][cid * 8]);
            }
        }
        __syncthreads();

        #pragma unroll
        for (int ks = 0; ks < 2; ++ks) {
            short8 a[2];
            #pragma unroll
            for (int i = 0; i < 2; ++i) {
                const int r = wr * 32 + i * 16 + l16;
                const int ph = (ks * 4 + quad) ^ (r & 7);
                a[i] = *(short8*)&As[r * 64 + ph * 8];
            }
            short8 bq[4];
            #pragma unroll
            for (int j = 0; j < 4; ++j) {
                const int r = wc * 64 + j * 16 + l16;
                const int ph = (ks * 4 + quad) ^ (r & 7);
                bq[j] = *(short8*)&Bs[0][r * 64 + ph * 8];
            }
            #pragma unroll
            for (int i = 0; i < 2; ++i)
                #pragma unroll
                for (int j = 0; j < 4; ++j)
                    accq[i][j] = __builtin_amdgcn_mfma_f32_16x16x32_bf16(
                        a[i], bq[j], accq[i][j], 0, 0, 0);
            if (kv) {
                short8 bk[4], bv[4];
                #pragma unroll
                for (int j = 0; j < 4; ++j) {
                    const int r = wc * 64 + j * 16 + l16;
                    const int ph = (ks * 4 + quad) ^ (r & 7);
                    bk[j] = *(short8*)&Bs[1][r * 64 + ph * 8];
                    bv[j] = *(short8*)&Bs[2][r * 64 + ph * 8];
                }
                #pragma unroll
                for (int i = 0; i < 2; ++i)
                    #pragma unroll
                    for (int j = 0; j < 4; ++j) {
                        acck[i][j] = __builtin_amdgcn_mfma_f32_16x16x32_bf16(
                            a[i], bk[j], acck[i][j], 0, 0, 0);
                        accv[i][j] = __builtin_amdgcn_mfma_f32_16x16x32_bf16(
                            a[i], bv[j], accv[i][j], 0, 0, 0);
                    }
            }
        }
    }

    // epilogue: +bias, scatter into head layouts.
    #pragma unroll
    for (int j = 0; j < 4; ++j) {
        const int col = n0 + wc * 64 + j * 16 + l16;
        const int h = col >> 6, dk = col & (DK_ - 1);
        const float bvq = b0[col], bvk = b1[col], bvv = b2[col];
        #pragma unroll
        for (int i = 0; i < 2; ++i) {
            #pragma unroll
            for (int rr = 0; rr < 4; ++rr) {
                const int row = m0 + wr * 32 + i * 16 + quad * 4 + rr;
                const int s = row & (S_ - 1);
                const size_t hdr = ((size_t)(bidx * H_ + h) * S_ + s) * DK_ + dk;
                qkv[hdr] = f32_to_bf16bits((accq[i][j][rr] + bvq) * QSCALE);
                if (kv) {
                    qkv[(size_t)M_ * D_ + hdr] =
                        f32_to_bf16bits(acck[i][j][rr] + bvk);
                    qkv[(size_t)2 * M_ * D_ +
                        ((size_t)(bidx * H_ + h) * DK_ + dk) * S_ + s] =
                        f32_to_bf16bits(accv[i][j][rr] + bvv);
                }
            }
        }
    }
}

// ---------------------------------------------------------------------------
// attention v4: v3 structure (64 q-rows/block, P folded into Q buffer, 40 KB
// LDS, 4 blocks/CU) + ONE change: bijective XCD-chunk blockIdx swizzle.
// Post-mortem chain: occupancy saturates at ~8 waves/CU (v1/v2/v3 curve) and
// LDS-traffic cuts don't help -> stall-bound on K/V glds completion latency.
// Default linear dispatch round-robins the 32 q-blocks of each head across
// all 8 XCDs: per-XCD K/V working set = ALL 32 heads = up to 16 MB >> 4 MB
// L2 -> per-kt tile fetches miss L2 (FETCH_SIZE 45 MB ~ 6x unique bytes =
// cross-XCD replication signature).  Swizzle work = (bid%8)*128 + bid/8
// gives each XCD 4 complete heads: <=2 MB K/V + 1 MB Q, L2-resident, and the
// 32 q-blocks of a head progress in lockstep so one L2 fill serves all.
// S^T trick (S^T = K*Q^T) -> packed P writes.  Row-sums via ones-MFMA reuse
// the PV A-fragment; rowsum lands in the exact lane that normalizes (zero
// shuffles).  P packed by TRUNCATION (bias cancels in the P/sum ratio).
// Q pre-scaled at projection: exp = bare v_exp_f32.
// ---------------------------------------------------------------------------
__global__ __launch_bounds__(256, 4) void attention(
    const ushort* __restrict__ qkv, const int* __restrict__ length,
    float* __restrict__ out)
{
    // XCD-chunk swizzle: 1024 blocks, 8 XCDs, 128 works/XCD (bijective).
    // work layout: qblk fastest, then h, then b -> chunk = 4 whole heads.
    const int bid  = blockIdx.x;
    const int work = (bid & 7) * 128 + (bid >> 3);
    const int q0 = (work & 31) * 64;
    const int h  = (work >> 5) & 15;
    const int b  = work >> 9;

    int len = length[b];
    if (len > S_) len = S_;
    if (len < 1) len = 1;
    const int nkt = (len + 63) >> 6;

    const ushort* qb = qkv + ((size_t)(b * H_ + h) * S_ + q0) * DK_;
    const ushort* kb = qkv + (size_t)M_ * D_ + (size_t)(b * H_ + h) * S_ * DK_;
    const ushort* vb = qkv + (size_t)2 * M_ * D_ + (size_t)(b * H_ + h) * DK_ * S_;

    __shared__ __align__(16) ushort QPs[64 * 64];      //  8 KB [q][dk] then [q][key]
    __shared__ __align__(16) ushort Ks[2][64 * 64];    // 16 KB [key][dk]
    __shared__ __align__(16) ushort Vs[2][64 * 64];    // 16 KB [dk][key]

    const int t = threadIdx.x, lane = t & 63, wid = t >> 6;
    const int quad = lane >> 4, l16 = lane & 15;
    const int qrow = wid * 16 + l16;
    const int e8 = (l16 & 7) << 1;   // even XOR phase for P chunks (row&7 == l16&7)

    // stage Q (once; each wave stages its own 16-row strip) + K/V tile 0
    #pragma unroll
    for (int j = 0; j < 2; ++j) {
        const int cid = wid * 128 + j * 64 + lane;
        const int row = cid >> 3;
        const int cl  = (cid & 7) ^ (row & 7);
        glds16(qb + (size_t)row * DK_ + cl * 8, &QPs[cid * 8]);
        glds16(kb + (size_t)row * DK_ + cl * 8, &Ks[0][cid * 8]);
        glds16(vb + (size_t)row * S_ + cl * 8,  &Vs[0][cid * 8]);
    }
    __syncthreads();

    // hoist Q fragments (loop-invariant); the wave's QPs strip is dead after
    // this and becomes its P buffer.  Same-wave in-order DS pipe guarantees
    // these reads complete before the first P write.
    short8 qfrag[2];
    #pragma unroll
    for (int ks = 0; ks < 2; ++ks) {
        const int phb = (ks * 4 + quad) ^ (l16 & 7);
        qfrag[ks] = *(short8*)&QPs[qrow * 64 + phb * 8];
    }

    // bf16 ones fragment for the rowsum MFMA
    short8 ones8;
    #pragma unroll
    for (int i = 0; i < 8; ++i) ones8[i] = (short)0x3F80;

    float4v cacc[4] = {};
    float4v racc = {};

    for (int kt = 0; kt < nkt; ++kt) {
        const int cur = kt & 1, nxt = cur ^ 1;
        if (kt + 1 < nkt) {
            #pragma unroll
            for (int j = 0; j < 2; ++j) {
                const int cid = wid * 128 + j * 64 + lane;
                const int row = cid >> 3;
                const int cl  = (cid & 7) ^ (row & 7);
                glds16(kb + (size_t)((kt + 1) * 64 + row) * DK_ + cl * 8,
                       &Ks[nxt][cid * 8]);
                glds16(vb + (size_t)row * S_ + (kt + 1) * 64 + cl * 8,
                       &Vs[nxt][cid * 8]);
            }
        }

        // S^T tile: A = K-frag (m=key), B = Q-frag (n=q).  D[key][q]:
        // lane holds q = l16 (col), keys = ct*16 + quad*4 + rr (rows).
        float4v sacc[4] = {};
        #pragma unroll
        for (int ks = 0; ks < 2; ++ks) {
            #pragma unroll
            for (int ct = 0; ct < 4; ++ct) {
                const int krow = ct * 16 + l16;
                const int pha = (ks * 4 + quad) ^ (krow & 7);
                short8 ak = *(short8*)&Ks[cur][krow * 64 + pha * 8];
                sacc[ct] = __builtin_amdgcn_mfma_f32_16x16x32_bf16(
                    ak, qfrag[ks], sacc[ct], 0, 0, 0);
            }
        }

        // exp2 + (boundary-only) mask + truncation-packed P write
        const bool full = ((kt + 1) * 64 <= len);
        #pragma unroll
        for (int ct = 0; ct < 4; ++ct) {
            float v0 = __builtin_amdgcn_exp2f(sacc[ct][0]);
            float v1 = __builtin_amdgcn_exp2f(sacc[ct][1]);
            float v2 = __builtin_amdgcn_exp2f(sacc[ct][2]);
            float v3 = __builtin_amdgcn_exp2f(sacc[ct][3]);
            if (!full) {
                const int kb0 = kt * 64 + ct * 16 + quad * 4;
                v0 = (kb0 + 0 < len) ? v0 : 0.f;
                v1 = (kb0 + 1 < len) ? v1 : 0.f;
                v2 = (kb0 + 2 < len) ? v2 : 0.f;
                v3 = (kb0 + 3 < len) ? v3 : 0.f;
            }
            uint2 w;
            w.x = (__float_as_uint(v0) >> 16) | (__float_as_uint(v1) & 0xFFFF0000u);
            w.y = (__float_as_uint(v2) >> 16) | (__float_as_uint(v3) & 0xFFFF0000u);
            const int c8 = (ct * 4 + quad) ^ e8;        // 8B-chunk swizzle
            *(uint2*)&QPs[qrow * 64 + c8 * 4] = w;
        }

        // P @ V  (+ rowsum via ones-MFMA, reusing the A-fragment).
        // Strip is wave-private: same-wave LDS RAW, no barrier needed.
        #pragma unroll
        for (int ks = 0; ks < 2; ++ks) {
            const int pp = ((ks * 4 + quad) * 2) ^ e8;   // first 8B chunk (even)
            short8 ap = *(short8*)&QPs[qrow * 64 + pp * 4];
            #pragma unroll
            for (int ct = 0; ct < 4; ++ct) {
                const int vrow = ct * 16 + l16;
                const int phv = (ks * 4 + quad) ^ (vrow & 7);
                short8 vv = *(short8*)&Vs[cur][vrow * 64 + phv * 8];
                cacc[ct] = __builtin_amdgcn_mfma_f32_16x16x32_bf16(
                    ap, vv, cacc[ct], 0, 0, 0);
            }
            racc = __builtin_amdgcn_mfma_f32_16x16x32_bf16(
                ap, ones8, racc, 0, 0, 0);
        }
        __syncthreads();   // next-stage glds drained; buf[cur] free for kt+2
    }

    // normalize + store fp32.  racc[rr] holds rowsum for q = quad*4+rr in
    // every l16 lane -- exactly where cacc[ct][rr] needs it.  No shuffles.
    #pragma unroll
    for (int rr = 0; rr < 4; ++rr) {
        const float inv = 1.0f / (racc[rr] + 1e-8f);
        const int q = q0 + wid * 16 + quad * 4 + rr;
        #pragma unroll
        for (int ct = 0; ct < 4; ++ct) {
            const int d = h * 64 + ct * 16 + l16;
            out[((size_t)b * S_ + q) * D_ + d] = cacc[ct][rr] * inv;
        }
    }
}

// ---------------------------------------------------------------------------
extern "C" void kernel_launch(void* const* d_in, const int* in_sizes, int n_in,
                              void* d_out, int out_size, void* d_ws, size_t ws_size,
                              hipStream_t stream)
{
    const float* Q   = (const float*)d_in[0];
    const int*   len = (const int*)d_in[1];
    const float* Wq  = (const float*)d_in[2];
    const float* bq  = (const float*)d_in[3];
    const float* Wk  = (const float*)d_in[4];
    const float* bk  = (const float*)d_in[5];
    const float* Wv  = (const float*)d_in[6];
    const float* bv  = (const float*)d_in[7];
    float* out = (float*)d_out;

    ushort* ws  = (ushort*)d_ws;
    ushort* Xb  = ws;                                   // 4M bf16 = 8 MB
    ushort* Wt  = ws + (size_t)M_ * D_;                 // 3M bf16 = 6 MB
    ushort* qkv = Wt + (size_t)3 * D_ * D_;             // 12M bf16 = 24 MB

    dim3 gPr(16, 16, 11);
    prep<<<gPr, 256, 0, stream>>>(Q, Wq, Wk, Wv, Xb, Wt);

    dim3 gP(M_ / 64, D_ / 128);
    proj_gemm<<<gP, 256, 0, stream>>>(Xb, Wt, bq, bk, bv, len, qkv);

    attention<<<dim3(S_ / 64 * H_ * B_), 256, 0, stream>>>(qkv, len, out);
}

// Round 5
// 157.419 us; speedup vs baseline: 1.0516x; 1.0516x over previous
//
#include <hip/hip_runtime.h>
#include <hip/hip_bf16.h>

#define B_  2
#define S_  2048
#define D_  1024
#define H_  16
#define DK_ 64
#define M_  (B_ * S_)   // 4096

typedef short short8 __attribute__((ext_vector_type(8)));
typedef float float4v __attribute__((ext_vector_type(4)));

// log2(e)/8 : folded into Q at projection so attention exp is a bare v_exp_f32
#define QSCALE 0.18033688011112042f

static __device__ __forceinline__ ushort f32_to_bf16bits(float f) {
    union { __hip_bfloat16 h; ushort u; } cv;
    cv.h = __float2bfloat16(f);
    return cv.u;
}

// async global->LDS, 16B per lane (lands at wave-uniform base + lane*16)
static __device__ __forceinline__ void glds16(const ushort* g, ushort* l) {
    __builtin_amdgcn_global_load_lds(
        (const __attribute__((address_space(1))) unsigned int*)g,
        (__attribute__((address_space(3))) unsigned int*)l, 16, 0, 0);
}

// ---------------------------------------------------------------------------
// prep: z in [0,3) -> transpose+convert W_z[k][n] fp32 -> Wt[n][k] bf16
//       z in [3,11) -> convert X fp32 -> bf16
// ---------------------------------------------------------------------------
__global__ __launch_bounds__(256) void prep(
    const float* __restrict__ X, const float* __restrict__ W0,
    const float* __restrict__ W1, const float* __restrict__ W2,
    ushort* __restrict__ Xb, ushort* __restrict__ Wt)
{
    const int z = blockIdx.z;
    const int t = threadIdx.x;

    if (z >= 3) {   // convert X
        const int blk = (z - 3) * 256 + blockIdx.y * 16 + blockIdx.x;
        const int i = blk * 2048 + t * 8;
        float4v a = *(const float4v*)(X + i);
        float4v b = *(const float4v*)(X + i + 4);
        short8 o;
        o[0] = (short)f32_to_bf16bits(a[0]); o[1] = (short)f32_to_bf16bits(a[1]);
        o[2] = (short)f32_to_bf16bits(a[2]); o[3] = (short)f32_to_bf16bits(a[3]);
        o[4] = (short)f32_to_bf16bits(b[0]); o[5] = (short)f32_to_bf16bits(b[1]);
        o[6] = (short)f32_to_bf16bits(b[2]); o[7] = (short)f32_to_bf16bits(b[3]);
        *(short8*)(Xb + i) = o;
        return;
    }

    const float* W = (z == 0) ? W0 : ((z == 1) ? W1 : W2);
    ushort* out = Wt + (size_t)z * D_ * D_;

    __shared__ ushort tile[64 * 72];
    int n0 = blockIdx.x * 64, k0 = blockIdx.y * 64;
    int r = t >> 3, g = t & 7;

    #pragma unroll
    for (int p = 0; p < 2; ++p) {
        int rr = r + p * 32;
        const float* src = W + (size_t)(k0 + rr) * D_ + n0 + g * 8;
        float4v a = *(const float4v*)src;
        float4v b = *(const float4v*)(src + 4);
        short8 o;
        o[0] = (short)f32_to_bf16bits(a[0]); o[1] = (short)f32_to_bf16bits(a[1]);
        o[2] = (short)f32_to_bf16bits(a[2]); o[3] = (short)f32_to_bf16bits(a[3]);
        o[4] = (short)f32_to_bf16bits(b[0]); o[5] = (short)f32_to_bf16bits(b[1]);
        o[6] = (short)f32_to_bf16bits(b[2]); o[7] = (short)f32_to_bf16bits(b[3]);
        *(short8*)&tile[rr * 72 + g * 8] = o;
    }
    __syncthreads();
    #pragma unroll
    for (int p = 0; p < 2; ++p) {
        int rr = r + p * 32;
        short8 v;
        #pragma unroll
        for (int i = 0; i < 8; ++i)
            v[i] = (short)tile[(g * 8 + i) * 72 + rr];
        *(short8*)(out + (size_t)(n0 + rr) * D_ + k0 + g * 8) = v;
    }
}

// ---------------------------------------------------------------------------
// FUSED-z QKV projection: one block = (m-tile 64, n-tile 128) computing q, k
// AND v.  A staged once, 48 MFMA per barrier.  56 KB LDS = 2 blocks/CU.
// k/v work skipped (block-uniform) when this m-tile is beyond length[b].
// z==0 (Q) epilogue folds score-scale*log2(e) into the values.
// ---------------------------------------------------------------------------
__global__ __launch_bounds__(256, 2) void proj_gemm(
    const ushort* __restrict__ X,    // [4096][1024] bf16
    const ushort* __restrict__ Wt,   // [3][1024][1024] bf16, n-major
    const float* __restrict__ b0, const float* __restrict__ b1,
    const float* __restrict__ b2,
    const int* __restrict__ length,
    ushort* __restrict__ qkv)        // [3][4M] bf16
{
    const int m0 = blockIdx.x * 64, n0 = blockIdx.y * 128;
    const int bidx = m0 >> 11;
    const int s0 = m0 & (S_ - 1);
    const bool kv = (s0 < length[bidx]);   // block-uniform

    __shared__ __align__(16) ushort As[64 * 64];        //  8 KB
    __shared__ __align__(16) ushort Bs[3][128 * 64];    // 48 KB

    const int t = threadIdx.x;
    const int lane = t & 63, wid = t >> 6;
    const int quad = lane >> 4, l16 = lane & 15;
    const int wr = wid >> 1, wc = wid & 1;

    float4v accq[2][4] = {}, acck[2][4] = {}, accv[2][4] = {};

    for (int kt = 0; kt < 16; ++kt) {
        const int k0 = kt * 64;
        __syncthreads();
        #pragma unroll
        for (int j = 0; j < 2; ++j) {          // A: 512 chunks, 128/wave
            const int cid = wid * 128 + j * 64 + lane;
            const int row = cid >> 3;
            const int cl  = (cid & 7) ^ (row & 7);
            glds16(X + (size_t)(m0 + row) * D_ + k0 + cl * 8, &As[cid * 8]);
        }
        #pragma unroll
        for (int j = 0; j < 4; ++j) {          // B panels: 1024 chunks each
            const int cid = wid * 256 + j * 64 + lane;
            const int row = cid >> 3;
            const int cl  = (cid & 7) ^ (row & 7);
            const size_t off = (size_t)(n0 + row) * D_ + k0 + cl * 8;
            glds16(Wt + off, &Bs[0][cid * 8]);
            if (kv) {
                glds16(Wt + (size_t)D_ * D_ + off,     &Bs[1][cid * 8]);
                glds16(Wt + (size_t)2 * D_ * D_ + off, &Bs[2][cid * 8]);
            }
        }
        __syncthreads();

        #pragma unroll
        for (int ks = 0; ks < 2; ++ks) {
            short8 a[2];
            #pragma unroll
            for (int i = 0; i < 2; ++i) {
                const int r = wr * 32 + i * 16 + l16;
                const int ph = (ks * 4 + quad) ^ (r & 7);
                a[i] = *(short8*)&As[r * 64 + ph * 8];
            }
            short8 bq[4];
            #pragma unroll
            for (int j = 0; j < 4; ++j) {
                const int r = wc * 64 + j * 16 + l16;
                const int ph = (ks * 4 + quad) ^ (r & 7);
                bq[j] = *(short8*)&Bs[0][r * 64 + ph * 8];
            }
            #pragma unroll
            for (int i = 0; i < 2; ++i)
                #pragma unroll
                for (int j = 0; j < 4; ++j)
                    accq[i][j] = __builtin_amdgcn_mfma_f32_16x16x32_bf16(
                        a[i], bq[j], accq[i][j], 0, 0, 0);
            if (kv) {
                short8 bk[4], bv[4];
                #pragma unroll
                for (int j = 0; j < 4; ++j) {
                    const int r = wc * 64 + j * 16 + l16;
                    const int ph = (ks * 4 + quad) ^ (r & 7);
                    bk[j] = *(short8*)&Bs[1][r * 64 + ph * 8];
                    bv[j] = *(short8*)&Bs[2][r * 64 + ph * 8];
                }
                #pragma unroll
                for (int i = 0; i < 2; ++i)
                    #pragma unroll
                    for (int j = 0; j < 4; ++j) {
                        acck[i][j] = __builtin_amdgcn_mfma_f32_16x16x32_bf16(
                            a[i], bk[j], acck[i][j], 0, 0, 0);
                        accv[i][j] = __builtin_amdgcn_mfma_f32_16x16x32_bf16(
                            a[i], bv[j], accv[i][j], 0, 0, 0);
                    }
            }
        }
    }

    // epilogue: +bias, scatter into head layouts.
    #pragma unroll
    for (int j = 0; j < 4; ++j) {
        const int col = n0 + wc * 64 + j * 16 + l16;
        const int h = col >> 6, dk = col & (DK_ - 1);
        const float bvq = b0[col], bvk = b1[col], bvv = b2[col];
        #pragma unroll
        for (int i = 0; i < 2; ++i) {
            #pragma unroll
            for (int rr = 0; rr < 4; ++rr) {
                const int row = m0 + wr * 32 + i * 16 + quad * 4 + rr;
                const int s = row & (S_ - 1);
                const size_t hdr = ((size_t)(bidx * H_ + h) * S_ + s) * DK_ + dk;
                qkv[hdr] = f32_to_bf16bits((accq[i][j][rr] + bvq) * QSCALE);
                if (kv) {
                    qkv[(size_t)M_ * D_ + hdr] =
                        f32_to_bf16bits(acck[i][j][rr] + bvk);
                    qkv[(size_t)2 * M_ * D_ +
                        ((size_t)(bidx * H_ + h) * DK_ + dk) * S_ + s] =
                        f32_to_bf16bits(accv[i][j][rr] + bvv);
                }
            }
        }
    }
}

// ---------------------------------------------------------------------------
// attention v5: v4 (XCD-chunk swizzle, P folded into Q buffer, 40 KB LDS,
// 4 blocks/CU) with ONE change: the work index is ordered (h, b, qblk)
// instead of (b, h, qblk).
// v4 post-mortem: swizzle cut FETCH_SIZE 45 -> 9.2 MB (L2-replication
// diagnosis CONFIRMED) but dur rose 44.6 -> 56 us because b = work>>9 put
// batch 0 entirely on XCDs 0-3 and batch 1 on XCDs 4-7; with random lengths
// the shorter batch's XCDs idle after it finishes (occupancy 29.6 -> 22.4).
// New decode: bh = work>>5, b = bh&1, h = bh>>1 -> each XCD's 128-work chunk
// is 2 heads of EACH batch (~3 MB K/V+Q, still L2-resident) and every CU's
// 4 resident blocks are 2x b0 + 2x b1: identical nkt0+nkt1 mix everywhere.
// S^T trick (S^T = K*Q^T) -> packed P writes.  Row-sums via ones-MFMA reuse
// the PV A-fragment; rowsum lands in the exact lane that normalizes (zero
// shuffles).  P packed by TRUNCATION (bias cancels in the P/sum ratio).
// Q pre-scaled at projection: exp = bare v_exp_f32.
// ---------------------------------------------------------------------------
__global__ __launch_bounds__(256, 4) void attention(
    const ushort* __restrict__ qkv, const int* __restrict__ length,
    float* __restrict__ out)
{
    // XCD-chunk swizzle: 1024 blocks, 8 XCDs, 128 works/XCD (bijective).
    // work layout: qblk fastest, then b, then h -> chunk = 4 (b,h) pairs
    // spanning BOTH batches (balanced) and only 2 distinct heads (L2-local).
    const int bid  = blockIdx.x;
    const int work = (bid & 7) * 128 + (bid >> 3);
    const int q0 = (work & 31) * 64;
    const int bh = work >> 5;          // 0..31
    const int b  = bh & 1;
    const int h  = bh >> 1;

    int len = length[b];
    if (len > S_) len = S_;
    if (len < 1) len = 1;
    const int nkt = (len + 63) >> 6;

    const ushort* qb = qkv + ((size_t)(b * H_ + h) * S_ + q0) * DK_;
    const ushort* kb = qkv + (size_t)M_ * D_ + (size_t)(b * H_ + h) * S_ * DK_;
    const ushort* vb = qkv + (size_t)2 * M_ * D_ + (size_t)(b * H_ + h) * DK_ * S_;

    __shared__ __align__(16) ushort QPs[64 * 64];      //  8 KB [q][dk] then [q][key]
    __shared__ __align__(16) ushort Ks[2][64 * 64];    // 16 KB [key][dk]
    __shared__ __align__(16) ushort Vs[2][64 * 64];    // 16 KB [dk][key]

    const int t = threadIdx.x, lane = t & 63, wid = t >> 6;
    const int quad = lane >> 4, l16 = lane & 15;
    const int qrow = wid * 16 + l16;
    const int e8 = (l16 & 7) << 1;   // even XOR phase for P chunks (row&7 == l16&7)

    // stage Q (once; each wave stages its own 16-row strip) + K/V tile 0
    #pragma unroll
    for (int j = 0; j < 2; ++j) {
        const int cid = wid * 128 + j * 64 + lane;
        const int row = cid >> 3;
        const int cl  = (cid & 7) ^ (row & 7);
        glds16(qb + (size_t)row * DK_ + cl * 8, &QPs[cid * 8]);
        glds16(kb + (size_t)row * DK_ + cl * 8, &Ks[0][cid * 8]);
        glds16(vb + (size_t)row * S_ + cl * 8,  &Vs[0][cid * 8]);
    }
    __syncthreads();

    // hoist Q fragments (loop-invariant); the wave's QPs strip is dead after
    // this and becomes its P buffer.  Same-wave in-order DS pipe guarantees
    // these reads complete before the first P write.
    short8 qfrag[2];
    #pragma unroll
    for (int ks = 0; ks < 2; ++ks) {
        const int phb = (ks * 4 + quad) ^ (l16 & 7);
        qfrag[ks] = *(short8*)&QPs[qrow * 64 + phb * 8];
    }

    // bf16 ones fragment for the rowsum MFMA
    short8 ones8;
    #pragma unroll
    for (int i = 0; i < 8; ++i) ones8[i] = (short)0x3F80;

    float4v cacc[4] = {};
    float4v racc = {};

    for (int kt = 0; kt < nkt; ++kt) {
        const int cur = kt & 1, nxt = cur ^ 1;
        if (kt + 1 < nkt) {
            #pragma unroll
            for (int j = 0; j < 2; ++j) {
                const int cid = wid * 128 + j * 64 + lane;
                const int row = cid >> 3;
                const int cl  = (cid & 7) ^ (row & 7);
                glds16(kb + (size_t)((kt + 1) * 64 + row) * DK_ + cl * 8,
                       &Ks[nxt][cid * 8]);
                glds16(vb + (size_t)row * S_ + (kt + 1) * 64 + cl * 8,
                       &Vs[nxt][cid * 8]);
            }
        }

        // S^T tile: A = K-frag (m=key), B = Q-frag (n=q).  D[key][q]:
        // lane holds q = l16 (col), keys = ct*16 + quad*4 + rr (rows).
        float4v sacc[4] = {};
        #pragma unroll
        for (int ks = 0; ks < 2; ++ks) {
            #pragma unroll
            for (int ct = 0; ct < 4; ++ct) {
                const int krow = ct * 16 + l16;
                const int pha = (ks * 4 + quad) ^ (krow & 7);
                short8 ak = *(short8*)&Ks[cur][krow * 64 + pha * 8];
                sacc[ct] = __builtin_amdgcn_mfma_f32_16x16x32_bf16(
                    ak, qfrag[ks], sacc[ct], 0, 0, 0);
            }
        }

        // exp2 + (boundary-only) mask + truncation-packed P write
        const bool full = ((kt + 1) * 64 <= len);
        #pragma unroll
        for (int ct = 0; ct < 4; ++ct) {
            float v0 = __builtin_amdgcn_exp2f(sacc[ct][0]);
            float v1 = __builtin_amdgcn_exp2f(sacc[ct][1]);
            float v2 = __builtin_amdgcn_exp2f(sacc[ct][2]);
            float v3 = __builtin_amdgcn_exp2f(sacc[ct][3]);
            if (!full) {
                const int kb0 = kt * 64 + ct * 16 + quad * 4;
                v0 = (kb0 + 0 < len) ? v0 : 0.f;
                v1 = (kb0 + 1 < len) ? v1 : 0.f;
                v2 = (kb0 + 2 < len) ? v2 : 0.f;
                v3 = (kb0 + 3 < len) ? v3 : 0.f;
            }
            uint2 w;
            w.x = (__float_as_uint(v0) >> 16) | (__float_as_uint(v1) & 0xFFFF0000u);
            w.y = (__float_as_uint(v2) >> 16) | (__float_as_uint(v3) & 0xFFFF0000u);
            const int c8 = (ct * 4 + quad) ^ e8;        // 8B-chunk swizzle
            *(uint2*)&QPs[qrow * 64 + c8 * 4] = w;
        }

        // P @ V  (+ rowsum via ones-MFMA, reusing the A-fragment).
        // Strip is wave-private: same-wave LDS RAW, no barrier needed.
        #pragma unroll
        for (int ks = 0; ks < 2; ++ks) {
            const int pp = ((ks * 4 + quad) * 2) ^ e8;   // first 8B chunk (even)
            short8 ap = *(short8*)&QPs[qrow * 64 + pp * 4];
            #pragma unroll
            for (int ct = 0; ct < 4; ++ct) {
                const int vrow = ct * 16 + l16;
                const int phv = (ks * 4 + quad) ^ (vrow & 7);
                short8 vv = *(short8*)&Vs[cur][vrow * 64 + phv * 8];
                cacc[ct] = __builtin_amdgcn_mfma_f32_16x16x32_bf16(
                    ap, vv, cacc[ct], 0, 0, 0);
            }
            racc = __builtin_amdgcn_mfma_f32_16x16x32_bf16(
                ap, ones8, racc, 0, 0, 0);
        }
        __syncthreads();   // next-stage glds drained; buf[cur] free for kt+2
    }

    // normalize + store fp32.  racc[rr] holds rowsum for q = quad*4+rr in
    // every l16 lane -- exactly where cacc[ct][rr] needs it.  No shuffles.
    #pragma unroll
    for (int rr = 0; rr < 4; ++rr) {
        const float inv = 1.0f / (racc[rr] + 1e-8f);
        const int q = q0 + wid * 16 + quad * 4 + rr;
        #pragma unroll
        for (int ct = 0; ct < 4; ++ct) {
            const int d = h * 64 + ct * 16 + l16;
            out[((size_t)b * S_ + q) * D_ + d] = cacc[ct][rr] * inv;
        }
    }
}

// ---------------------------------------------------------------------------
extern "C" void kernel_launch(void* const* d_in, const int* in_sizes, int n_in,
                              void* d_out, int out_size, void* d_ws, size_t ws_size,
                              hipStream_t stream)
{
    const float* Q   = (const float*)d_in[0];
    const int*   len = (const int*)d_in[1];
    const float* Wq  = (const float*)d_in[2];
    const float* bq  = (const float*)d_in[3];
    const float* Wk  = (const float*)d_in[4];
    const float* bk  = (const float*)d_in[5];
    const float* Wv  = (const float*)d_in[6];
    const float* bv  = (const float*)d_in[7];
    float* out = (float*)d_out;

    ushort* ws  = (ushort*)d_ws;
    ushort* Xb  = ws;                                   // 4M bf16 = 8 MB
    ushort* Wt  = ws + (size_t)M_ * D_;                 // 3M bf16 = 6 MB
    ushort* qkv = Wt + (size_t)3 * D_ * D_;             // 12M bf16 = 24 MB

    dim3 gPr(16, 16, 11);
    prep<<<gPr, 256, 0, stream>>>(Q, Wq, Wk, Wv, Xb, Wt);

    dim3 gP(M_ / 64, D_ / 128);
    proj_gemm<<<gP, 256, 0, stream>>>(Xb, Wt, bq, bk, bv, len, qkv);

    attention<<<dim3(S_ / 64 * H_ * B_), 256, 0, stream>>>(qkv, len, out);
}

// Round 6
// 153.997 us; speedup vs baseline: 1.0749x; 1.0222x over previous
//
#include <hip/hip_runtime.h>
#include <hip/hip_bf16.h>

#define B_  2
#define S_  2048
#define D_  1024
#define H_  16
#define DK_ 64
#define M_  (B_ * S_)   // 4096

typedef short short8 __attribute__((ext_vector_type(8)));
typedef float float4v __attribute__((ext_vector_type(4)));

// log2(e)/8 : folded into Q at projection so attention exp is a bare v_exp_f32
#define QSCALE 0.18033688011112042f

static __device__ __forceinline__ ushort f32_to_bf16bits(float f) {
    union { __hip_bfloat16 h; ushort u; } cv;
    cv.h = __float2bfloat16(f);
    return cv.u;
}

// async global->LDS, 16B per lane (lands at wave-uniform base + lane*16)
static __device__ __forceinline__ void glds16(const ushort* g, ushort* l) {
    __builtin_amdgcn_global_load_lds(
        (const __attribute__((address_space(1))) unsigned int*)g,
        (__attribute__((address_space(3))) unsigned int*)l, 16, 0, 0);
}

// ---------------------------------------------------------------------------
// prep: z in [0,3) -> transpose+convert W_z[k][n] fp32 -> Wt[n][k] bf16
//       z in [3,11) -> convert X fp32 -> bf16
// ---------------------------------------------------------------------------
__global__ __launch_bounds__(256) void prep(
    const float* __restrict__ X, const float* __restrict__ W0,
    const float* __restrict__ W1, const float* __restrict__ W2,
    ushort* __restrict__ Xb, ushort* __restrict__ Wt)
{
    const int z = blockIdx.z;
    const int t = threadIdx.x;

    if (z >= 3) {   // convert X
        const int blk = (z - 3) * 256 + blockIdx.y * 16 + blockIdx.x;
        const int i = blk * 2048 + t * 8;
        float4v a = *(const float4v*)(X + i);
        float4v b = *(const float4v*)(X + i + 4);
        short8 o;
        o[0] = (short)f32_to_bf16bits(a[0]); o[1] = (short)f32_to_bf16bits(a[1]);
        o[2] = (short)f32_to_bf16bits(a[2]); o[3] = (short)f32_to_bf16bits(a[3]);
        o[4] = (short)f32_to_bf16bits(b[0]); o[5] = (short)f32_to_bf16bits(b[1]);
        o[6] = (short)f32_to_bf16bits(b[2]); o[7] = (short)f32_to_bf16bits(b[3]);
        *(short8*)(Xb + i) = o;
        return;
    }

    const float* W = (z == 0) ? W0 : ((z == 1) ? W1 : W2);
    ushort* out = Wt + (size_t)z * D_ * D_;

    __shared__ ushort tile[64 * 72];
    int n0 = blockIdx.x * 64, k0 = blockIdx.y * 64;
    int r = t >> 3, g = t & 7;

    #pragma unroll
    for (int p = 0; p < 2; ++p) {
        int rr = r + p * 32;
        const float* src = W + (size_t)(k0 + rr) * D_ + n0 + g * 8;
        float4v a = *(const float4v*)src;
        float4v b = *(const float4v*)(src + 4);
        short8 o;
        o[0] = (short)f32_to_bf16bits(a[0]); o[1] = (short)f32_to_bf16bits(a[1]);
        o[2] = (short)f32_to_bf16bits(a[2]); o[3] = (short)f32_to_bf16bits(a[3]);
        o[4] = (short)f32_to_bf16bits(b[0]); o[5] = (short)f32_to_bf16bits(b[1]);
        o[6] = (short)f32_to_bf16bits(b[2]); o[7] = (short)f32_to_bf16bits(b[3]);
        *(short8*)&tile[rr * 72 + g * 8] = o;
    }
    __syncthreads();
    #pragma unroll
    for (int p = 0; p < 2; ++p) {
        int rr = r + p * 32;
        short8 v;
        #pragma unroll
        for (int i = 0; i < 8; ++i)
            v[i] = (short)tile[(g * 8 + i) * 72 + rr];
        *(short8*)(out + (size_t)(n0 + rr) * D_ + k0 + g * 8) = v;
    }
}

// ---------------------------------------------------------------------------
// FUSED-z QKV projection: one block = (m-tile 64, n-tile 128) computing q, k
// AND v.  A staged once, 48 MFMA per barrier.  56 KB LDS = 2 blocks/CU.
// k/v work skipped (block-uniform) when this m-tile is beyond length[b].
// z==0 (Q) epilogue folds score-scale*log2(e) into the values.
// ---------------------------------------------------------------------------
__global__ __launch_bounds__(256, 2) void proj_gemm(
    const ushort* __restrict__ X,    // [4096][1024] bf16
    const ushort* __restrict__ Wt,   // [3][1024][1024] bf16, n-major
    const float* __restrict__ b0, const float* __restrict__ b1,
    const float* __restrict__ b2,
    const int* __restrict__ length,
    ushort* __restrict__ qkv)        // [3][4M] bf16
{
    const int m0 = blockIdx.x * 64, n0 = blockIdx.y * 128;
    const int bidx = m0 >> 11;
    const int s0 = m0 & (S_ - 1);
    const bool kv = (s0 < length[bidx]);   // block-uniform

    __shared__ __align__(16) ushort As[64 * 64];        //  8 KB
    __shared__ __align__(16) ushort Bs[3][128 * 64];    // 48 KB

    const int t = threadIdx.x;
    const int lane = t & 63, wid = t >> 6;
    const int quad = lane >> 4, l16 = lane & 15;
    const int wr = wid >> 1, wc = wid & 1;

    float4v accq[2][4] = {}, acck[2][4] = {}, accv[2][4] = {};

    for (int kt = 0; kt < 16; ++kt) {
        const int k0 = kt * 64;
        __syncthreads();
        #pragma unroll
        for (int j = 0; j < 2; ++j) {          // A: 512 chunks, 128/wave
            const int cid = wid * 128 + j * 64 + lane;
            const int row = cid >> 3;
            const int cl  = (cid & 7) ^ (row & 7);
            glds16(X + (size_t)(m0 + row) * D_ + k0 + cl * 8, &As[cid * 8]);
        }
        #pragma unroll
        for (int j = 0; j < 4; ++j) {          // B panels: 1024 chunks each
            const int cid = wid * 256 + j * 64 + lane;
            const int row = cid >> 3;
            const int cl  = (cid & 7) ^ (row & 7);
            const size_t off = (size_t)(n0 + row) * D_ + k0 + cl * 8;
            glds16(Wt + off, &Bs[0][cid * 8]);
            if (kv) {
                glds16(Wt + (size_t)D_ * D_ + off,     &Bs[1][cid * 8]);
                glds16(Wt + (size_t)2 * D_ * D_ + off, &Bs[2][cid * 8]);
            }
        }
        __syncthreads();

        #pragma unroll
        for (int ks = 0; ks < 2; ++ks) {
            short8 a[2];
            #pragma unroll
            for (int i = 0; i < 2; ++i) {
                const int r = wr * 32 + i * 16 + l16;
                const int ph = (ks * 4 + quad) ^ (r & 7);
                a[i] = *(short8*)&As[r * 64 + ph * 8];
            }
            short8 bq[4];
            #pragma unroll
            for (int j = 0; j < 4; ++j) {
                const int r = wc * 64 + j * 16 + l16;
                const int ph = (ks * 4 + quad) ^ (r & 7);
                bq[j] = *(short8*)&Bs[0][r * 64 + ph * 8];
            }
            #pragma unroll
            for (int i = 0; i < 2; ++i)
                #pragma unroll
                for (int j = 0; j < 4; ++j)
                    accq[i][j] = __builtin_amdgcn_mfma_f32_16x16x32_bf16(
                        a[i], bq[j], accq[i][j], 0, 0, 0);
            if (kv) {
                short8 bk[4], bv[4];
                #pragma unroll
                for (int j = 0; j < 4; ++j) {
                    const int r = wc * 64 + j * 16 + l16;
                    const int ph = (ks * 4 + quad) ^ (r & 7);
                    bk[j] = *(short8*)&Bs[1][r * 64 + ph * 8];
                    bv[j] = *(short8*)&Bs[2][r * 64 + ph * 8];
                }
                #pragma unroll
                for (int i = 0; i < 2; ++i)
                    #pragma unroll
                    for (int j = 0; j < 4; ++j) {
                        acck[i][j] = __builtin_amdgcn_mfma_f32_16x16x32_bf16(
                            a[i], bk[j], acck[i][j], 0, 0, 0);
                        accv[i][j] = __builtin_amdgcn_mfma_f32_16x16x32_bf16(
                            a[i], bv[j], accv[i][j], 0, 0, 0);
                    }
            }
        }
    }

    // epilogue: +bias, scatter into head layouts.
    #pragma unroll
    for (int j = 0; j < 4; ++j) {
        const int col = n0 + wc * 64 + j * 16 + l16;
        const int h = col >> 6, dk = col & (DK_ - 1);
        const float bvq = b0[col], bvk = b1[col], bvv = b2[col];
        #pragma unroll
        for (int i = 0; i < 2; ++i) {
            #pragma unroll
            for (int rr = 0; rr < 4; ++rr) {
                const int row = m0 + wr * 32 + i * 16 + quad * 4 + rr;
                const int s = row & (S_ - 1);
                const size_t hdr = ((size_t)(bidx * H_ + h) * S_ + s) * DK_ + dk;
                qkv[hdr] = f32_to_bf16bits((accq[i][j][rr] + bvq) * QSCALE);
                if (kv) {
                    qkv[(size_t)M_ * D_ + hdr] =
                        f32_to_bf16bits(acck[i][j][rr] + bvk);
                    qkv[(size_t)2 * M_ * D_ +
                        ((size_t)(bidx * H_ + h) * DK_ + dk) * S_ + s] =
                        f32_to_bf16bits(accv[i][j][rr] + bvv);
                }
            }
        }
    }
}

// ---------------------------------------------------------------------------
// attention v6: v5 (XCD swizzle w/ balanced (h,b,qblk) decode, 64-row blocks)
// + ONE structural change: P NEVER TOUCHES LDS.
// v1-v5 post-mortem: every extensive knob (waves, LDS bytes, HBM bytes, L2
// locality) is null; all pipes <=30% -> per-iteration LATENCY CHAIN bound.
// The P ds_write -> ds_read turnaround (~200+ cy) sat on that chain.
// Fix: permute the K rows fed to each QK^T MFMA so each lane's S output IS
// its PV A-fragment:  krow(ct,l16) = (ct>>1)*32 + (l16>>2)*8 + (ct&1)*4 +
// (l16&3)  =>  lane (quad,l16) gets sacc[ct][rr] = S[key][q=l16] with
// key = (ct>>1)*32 + quad*8 + (ct&1)*4 + rr -- exactly PV's required
// keys ks*32 + quad*8 + j  (ct = 2ks + (j>>2), rr = j&3).  exp + truncation-
// pack happen in registers; PV consumes ap[ks] directly.  Zero cross-lane
// ops, zero P LDS traffic.  K storage hash becomes hK(r) = (r&3)|((r>>3&1)<<2)
// (write-side pre-swizzle + read-side XOR; keeps 8-slot balanced bank spread).
// Q is loaded straight to registers (2 short8/lane) -- QPs buffer dropped:
// LDS 40 -> 32 KB.  Row-sums via ones-MFMA reuse ap; rowsum lands in the
// exact lane that normalizes (zero shuffles).  Q pre-scaled at projection.
// ---------------------------------------------------------------------------
__global__ __launch_bounds__(256, 4) void attention(
    const ushort* __restrict__ qkv, const int* __restrict__ length,
    float* __restrict__ out)
{
    // XCD-chunk swizzle: 1024 blocks, 8 XCDs, 128 works/XCD (bijective).
    // work layout: qblk fastest, then b, then h -> chunk = 4 (b,h) pairs
    // spanning BOTH batches (balanced) and only 2 distinct heads (L2-local).
    const int bid  = blockIdx.x;
    const int work = (bid & 7) * 128 + (bid >> 3);
    const int q0 = (work & 31) * 64;
    const int bh = work >> 5;          // 0..31
    const int b  = bh & 1;
    const int h  = bh >> 1;

    int len = length[b];
    if (len > S_) len = S_;
    if (len < 1) len = 1;
    const int nkt = (len + 63) >> 6;

    const ushort* qb = qkv + ((size_t)(b * H_ + h) * S_ + q0) * DK_;
    const ushort* kb = qkv + (size_t)M_ * D_ + (size_t)(b * H_ + h) * S_ * DK_;
    const ushort* vb = qkv + (size_t)2 * M_ * D_ + (size_t)(b * H_ + h) * DK_ * S_;

    __shared__ __align__(16) ushort Ks[2][64 * 64];    // 16 KB [key][dk], hash hK
    __shared__ __align__(16) ushort Vs[2][64 * 64];    // 16 KB [dk][key], hash r&7

    const int t = threadIdx.x, lane = t & 63, wid = t >> 6;
    const int quad = lane >> 4, l16 = lane & 15;

    // K read-side constants: krow = kbase[ct] + klocal; hK(krow) = hk (per-lane)
    const int klocal = ((l16 >> 2) << 3) + (l16 & 3);
    const int hk     = (l16 & 3) | (((l16 >> 2) & 1) << 2);

    // Q fragments: straight from global, no LDS.
    // B-operand layout: lane (quad,l16) holds Q[q=l16 of strip][(ks*4+quad)*8+j]
    short8 qfrag[2];
    {
        const ushort* qp = qb + (size_t)(wid * 16 + l16) * DK_;
        qfrag[0] = *(const short8*)(qp + quad * 8);
        qfrag[1] = *(const short8*)(qp + (4 + quad) * 8);
    }

    // stage K/V tile 0 (K uses hK pre-swizzle on the global side)
    #pragma unroll
    for (int j = 0; j < 2; ++j) {
        const int cid = wid * 128 + j * 64 + lane;
        const int row = cid >> 3;
        const int c   = cid & 7;
        const int hKr = (row & 3) | (((row >> 3) & 1) << 2);
        glds16(kb + (size_t)row * DK_ + (c ^ hKr) * 8, &Ks[0][cid * 8]);
        glds16(vb + (size_t)row * S_ + (c ^ (row & 7)) * 8, &Vs[0][cid * 8]);
    }
    __syncthreads();

    // bf16 ones fragment for the rowsum MFMA
    short8 ones8;
    #pragma unroll
    for (int i = 0; i < 8; ++i) ones8[i] = (short)0x3F80;

    float4v cacc[4] = {};
    float4v racc = {};

    for (int kt = 0; kt < nkt; ++kt) {
        const int cur = kt & 1, nxt = cur ^ 1;
        if (kt + 1 < nkt) {
            #pragma unroll
            for (int j = 0; j < 2; ++j) {
                const int cid = wid * 128 + j * 64 + lane;
                const int row = cid >> 3;
                const int c   = cid & 7;
                const int hKr = (row & 3) | (((row >> 3) & 1) << 2);
                glds16(kb + (size_t)((kt + 1) * 64 + row) * DK_ + (c ^ hKr) * 8,
                       &Ks[nxt][cid * 8]);
                glds16(vb + (size_t)row * S_ + (kt + 1) * 64 + (c ^ (row & 7)) * 8,
                       &Vs[nxt][cid * 8]);
            }
        }

        // S^T with PV-aligned K-row permutation.  After this, lane (quad,l16)
        // holds sacc[ct][rr] = S[key=(ct>>1)*32+quad*8+(ct&1)*4+rr][q=l16].
        float4v sacc[4] = {};
        #pragma unroll
        for (int ks = 0; ks < 2; ++ks) {
            #pragma unroll
            for (int ct = 0; ct < 4; ++ct) {
                const int krow = ((ct >> 1) << 5) + ((ct & 1) << 2) + klocal;
                const int pha = (ks * 4 + quad) ^ hk;
                short8 ak = *(short8*)&Ks[cur][krow * 64 + pha * 8];
                sacc[ct] = __builtin_amdgcn_mfma_f32_16x16x32_bf16(
                    ak, qfrag[ks], sacc[ct], 0, 0, 0);
            }
        }

        // exp2 + (boundary-only) mask + truncation-pack -> PV A-frags in regs
        const bool full = ((kt + 1) * 64 <= len);
        short8 ap[2];
        #pragma unroll
        for (int ks = 0; ks < 2; ++ks) {
            union { uint u[4]; short8 s; } cv;
            #pragma unroll
            for (int hh = 0; hh < 2; ++hh) {
                const int ct = 2 * ks + hh;
                float e0 = __builtin_amdgcn_exp2f(sacc[ct][0]);
                float e1 = __builtin_amdgcn_exp2f(sacc[ct][1]);
                float e2 = __builtin_amdgcn_exp2f(sacc[ct][2]);
                float e3 = __builtin_amdgcn_exp2f(sacc[ct][3]);
                if (!full) {
                    const int kb0 = kt * 64 + ks * 32 + quad * 8 + hh * 4;
                    e0 = (kb0 + 0 < len) ? e0 : 0.f;
                    e1 = (kb0 + 1 < len) ? e1 : 0.f;
                    e2 = (kb0 + 2 < len) ? e2 : 0.f;
                    e3 = (kb0 + 3 < len) ? e3 : 0.f;
                }
                cv.u[hh * 2 + 0] = (__float_as_uint(e0) >> 16) |
                                   (__float_as_uint(e1) & 0xFFFF0000u);
                cv.u[hh * 2 + 1] = (__float_as_uint(e2) >> 16) |
                                   (__float_as_uint(e3) & 0xFFFF0000u);
            }
            ap[ks] = cv.s;
        }

        // P @ V  (+ rowsum via ones-MFMA, reusing ap).  P never touched LDS.
        #pragma unroll
        for (int ks = 0; ks < 2; ++ks) {
            #pragma unroll
            for (int ct = 0; ct < 4; ++ct) {
                const int vrow = ct * 16 + l16;
                const int phv = (ks * 4 + quad) ^ (vrow & 7);
                short8 vv = *(short8*)&Vs[cur][vrow * 64 + phv * 8];
                cacc[ct] = __builtin_amdgcn_mfma_f32_16x16x32_bf16(
                    ap[ks], vv, cacc[ct], 0, 0, 0);
            }
            racc = __builtin_amdgcn_mfma_f32_16x16x32_bf16(
                ap[ks], ones8, racc, 0, 0, 0);
        }
        __syncthreads();   // next-stage glds drained; buf[cur] free for kt+2
    }

    // normalize + store fp32.  racc[rr] holds rowsum for q = quad*4+rr in
    // every l16 lane -- exactly where cacc[ct][rr] needs it.  No shuffles.
    #pragma unroll
    for (int rr = 0; rr < 4; ++rr) {
        const float inv = 1.0f / (racc[rr] + 1e-8f);
        const int q = q0 + wid * 16 + quad * 4 + rr;
        #pragma unroll
        for (int ct = 0; ct < 4; ++ct) {
            const int d = h * 64 + ct * 16 + l16;
            out[((size_t)b * S_ + q) * D_ + d] = cacc[ct][rr] * inv;
        }
    }
}

// ---------------------------------------------------------------------------
extern "C" void kernel_launch(void* const* d_in, const int* in_sizes, int n_in,
                              void* d_out, int out_size, void* d_ws, size_t ws_size,
                              hipStream_t stream)
{
    const float* Q   = (const float*)d_in[0];
    const int*   len = (const int*)d_in[1];
    const float* Wq  = (const float*)d_in[2];
    const float* bq  = (const float*)d_in[3];
    const float* Wk  = (const float*)d_in[4];
    const float* bk  = (const float*)d_in[5];
    const float* Wv  = (const float*)d_in[6];
    const float* bv  = (const float*)d_in[7];
    float* out = (float*)d_out;

    ushort* ws  = (ushort*)d_ws;
    ushort* Xb  = ws;                                   // 4M bf16 = 8 MB
    ushort* Wt  = ws + (size_t)M_ * D_;                 // 3M bf16 = 6 MB
    ushort* qkv = Wt + (size_t)3 * D_ * D_;             // 12M bf16 = 24 MB

    dim3 gPr(16, 16, 11);
    prep<<<gPr, 256, 0, stream>>>(Q, Wq, Wk, Wv, Xb, Wt);

    dim3 gP(M_ / 64, D_ / 128);
    proj_gemm<<<gP, 256, 0, stream>>>(Xb, Wt, bq, bk, bv, len, qkv);

    attention<<<dim3(S_ / 64 * H_ * B_), 256, 0, stream>>>(qkv, len, out);
}

// Round 7
// 152.000 us; speedup vs baseline: 1.0891x; 1.0131x over previous
//
#include <hip/hip_runtime.h>
#include <hip/hip_bf16.h>

#define B_  2
#define S_  2048
#define D_  1024
#define H_  16
#define DK_ 64
#define M_  (B_ * S_)   // 4096

typedef short short8 __attribute__((ext_vector_type(8)));
typedef float float4v __attribute__((ext_vector_type(4)));

// log2(e)/8 : folded into Q at projection so attention exp is a bare v_exp_f32
#define QSCALE 0.18033688011112042f

static __device__ __forceinline__ ushort f32_to_bf16bits(float f) {
    union { __hip_bfloat16 h; ushort u; } cv;
    cv.h = __float2bfloat16(f);
    return cv.u;
}

// async global->LDS, 16B per lane (lands at wave-uniform base + lane*16)
static __device__ __forceinline__ void glds16(const ushort* g, ushort* l) {
    __builtin_amdgcn_global_load_lds(
        (const __attribute__((address_space(1))) unsigned int*)g,
        (__attribute__((address_space(3))) unsigned int*)l, 16, 0, 0);
}

// ---------------------------------------------------------------------------
// prep: z in [0,3) -> transpose+convert W_z[k][n] fp32 -> Wt[n][k] bf16
//       z in [3,11) -> convert X fp32 -> bf16
// ---------------------------------------------------------------------------
__global__ __launch_bounds__(256) void prep(
    const float* __restrict__ X, const float* __restrict__ W0,
    const float* __restrict__ W1, const float* __restrict__ W2,
    ushort* __restrict__ Xb, ushort* __restrict__ Wt)
{
    const int z = blockIdx.z;
    const int t = threadIdx.x;

    if (z >= 3) {   // convert X
        const int blk = (z - 3) * 256 + blockIdx.y * 16 + blockIdx.x;
        const int i = blk * 2048 + t * 8;
        float4v a = *(const float4v*)(X + i);
        float4v b = *(const float4v*)(X + i + 4);
        short8 o;
        o[0] = (short)f32_to_bf16bits(a[0]); o[1] = (short)f32_to_bf16bits(a[1]);
        o[2] = (short)f32_to_bf16bits(a[2]); o[3] = (short)f32_to_bf16bits(a[3]);
        o[4] = (short)f32_to_bf16bits(b[0]); o[5] = (short)f32_to_bf16bits(b[1]);
        o[6] = (short)f32_to_bf16bits(b[2]); o[7] = (short)f32_to_bf16bits(b[3]);
        *(short8*)(Xb + i) = o;
        return;
    }

    const float* W = (z == 0) ? W0 : ((z == 1) ? W1 : W2);
    ushort* out = Wt + (size_t)z * D_ * D_;

    __shared__ ushort tile[64 * 72];
    int n0 = blockIdx.x * 64, k0 = blockIdx.y * 64;
    int r = t >> 3, g = t & 7;

    #pragma unroll
    for (int p = 0; p < 2; ++p) {
        int rr = r + p * 32;
        const float* src = W + (size_t)(k0 + rr) * D_ + n0 + g * 8;
        float4v a = *(const float4v*)src;
        float4v b = *(const float4v*)(src + 4);
        short8 o;
        o[0] = (short)f32_to_bf16bits(a[0]); o[1] = (short)f32_to_bf16bits(a[1]);
        o[2] = (short)f32_to_bf16bits(a[2]); o[3] = (short)f32_to_bf16bits(a[3]);
        o[4] = (short)f32_to_bf16bits(b[0]); o[5] = (short)f32_to_bf16bits(b[1]);
        o[6] = (short)f32_to_bf16bits(b[2]); o[7] = (short)f32_to_bf16bits(b[3]);
        *(short8*)&tile[rr * 72 + g * 8] = o;
    }
    __syncthreads();
    #pragma unroll
    for (int p = 0; p < 2; ++p) {
        int rr = r + p * 32;
        short8 v;
        #pragma unroll
        for (int i = 0; i < 8; ++i)
            v[i] = (short)tile[(g * 8 + i) * 72 + rr];
        *(short8*)(out + (size_t)(n0 + rr) * D_ + k0 + g * 8) = v;
    }
}

// ---------------------------------------------------------------------------
// FUSED-z QKV projection: one block = (m-tile 64, n-tile 128) computing q, k
// AND v.  A staged once, 48 MFMA per barrier.  56 KB LDS = 2 blocks/CU.
// k/v work skipped (block-uniform) when this m-tile is beyond length[b].
// z==0 (Q) epilogue folds score-scale*log2(e) into the values.
// ---------------------------------------------------------------------------
__global__ __launch_bounds__(256, 2) void proj_gemm(
    const ushort* __restrict__ X,    // [4096][1024] bf16
    const ushort* __restrict__ Wt,   // [3][1024][1024] bf16, n-major
    const float* __restrict__ b0, const float* __restrict__ b1,
    const float* __restrict__ b2,
    const int* __restrict__ length,
    ushort* __restrict__ qkv)        // [3][4M] bf16
{
    const int m0 = blockIdx.x * 64, n0 = blockIdx.y * 128;
    const int bidx = m0 >> 11;
    const int s0 = m0 & (S_ - 1);
    const bool kv = (s0 < length[bidx]);   // block-uniform

    __shared__ __align__(16) ushort As[64 * 64];        //  8 KB
    __shared__ __align__(16) ushort Bs[3][128 * 64];    // 48 KB

    const int t = threadIdx.x;
    const int lane = t & 63, wid = t >> 6;
    const int quad = lane >> 4, l16 = lane & 15;
    const int wr = wid >> 1, wc = wid & 1;

    float4v accq[2][4] = {}, acck[2][4] = {}, accv[2][4] = {};

    for (int kt = 0; kt < 16; ++kt) {
        const int k0 = kt * 64;
        __syncthreads();
        #pragma unroll
        for (int j = 0; j < 2; ++j) {          // A: 512 chunks, 128/wave
            const int cid = wid * 128 + j * 64 + lane;
            const int row = cid >> 3;
            const int cl  = (cid & 7) ^ (row & 7);
            glds16(X + (size_t)(m0 + row) * D_ + k0 + cl * 8, &As[cid * 8]);
        }
        #pragma unroll
        for (int j = 0; j < 4; ++j) {          // B panels: 1024 chunks each
            const int cid = wid * 256 + j * 64 + lane;
            const int row = cid >> 3;
            const int cl  = (cid & 7) ^ (row & 7);
            const size_t off = (size_t)(n0 + row) * D_ + k0 + cl * 8;
            glds16(Wt + off, &Bs[0][cid * 8]);
            if (kv) {
                glds16(Wt + (size_t)D_ * D_ + off,     &Bs[1][cid * 8]);
                glds16(Wt + (size_t)2 * D_ * D_ + off, &Bs[2][cid * 8]);
            }
        }
        __syncthreads();

        #pragma unroll
        for (int ks = 0; ks < 2; ++ks) {
            short8 a[2];
            #pragma unroll
            for (int i = 0; i < 2; ++i) {
                const int r = wr * 32 + i * 16 + l16;
                const int ph = (ks * 4 + quad) ^ (r & 7);
                a[i] = *(short8*)&As[r * 64 + ph * 8];
            }
            short8 bq[4];
            #pragma unroll
            for (int j = 0; j < 4; ++j) {
                const int r = wc * 64 + j * 16 + l16;
                const int ph = (ks * 4 + quad) ^ (r & 7);
                bq[j] = *(short8*)&Bs[0][r * 64 + ph * 8];
            }
            #pragma unroll
            for (int i = 0; i < 2; ++i)
                #pragma unroll
                for (int j = 0; j < 4; ++j)
                    accq[i][j] = __builtin_amdgcn_mfma_f32_16x16x32_bf16(
                        a[i], bq[j], accq[i][j], 0, 0, 0);
            if (kv) {
                short8 bk[4], bv[4];
                #pragma unroll
                for (int j = 0; j < 4; ++j) {
                    const int r = wc * 64 + j * 16 + l16;
                    const int ph = (ks * 4 + quad) ^ (r & 7);
                    bk[j] = *(short8*)&Bs[1][r * 64 + ph * 8];
                    bv[j] = *(short8*)&Bs[2][r * 64 + ph * 8];
                }
                #pragma unroll
                for (int i = 0; i < 2; ++i)
                    #pragma unroll
                    for (int j = 0; j < 4; ++j) {
                        acck[i][j] = __builtin_amdgcn_mfma_f32_16x16x32_bf16(
                            a[i], bk[j], acck[i][j], 0, 0, 0);
                        accv[i][j] = __builtin_amdgcn_mfma_f32_16x16x32_bf16(
                            a[i], bv[j], accv[i][j], 0, 0, 0);
                    }
            }
        }
    }

    // epilogue: +bias, scatter into head layouts.
    #pragma unroll
    for (int j = 0; j < 4; ++j) {
        const int col = n0 + wc * 64 + j * 16 + l16;
        const int h = col >> 6, dk = col & (DK_ - 1);
        const float bvq = b0[col], bvk = b1[col], bvv = b2[col];
        #pragma unroll
        for (int i = 0; i < 2; ++i) {
            #pragma unroll
            for (int rr = 0; rr < 4; ++rr) {
                const int row = m0 + wr * 32 + i * 16 + quad * 4 + rr;
                const int s = row & (S_ - 1);
                const size_t hdr = ((size_t)(bidx * H_ + h) * S_ + s) * DK_ + dk;
                qkv[hdr] = f32_to_bf16bits((accq[i][j][rr] + bvq) * QSCALE);
                if (kv) {
                    qkv[(size_t)M_ * D_ + hdr] =
                        f32_to_bf16bits(acck[i][j][rr] + bvk);
                    qkv[(size_t)2 * M_ * D_ +
                        ((size_t)(bidx * H_ + h) * DK_ + dk) * S_ + s] =
                        f32_to_bf16bits(accv[i][j][rr] + bvv);
                }
            }
        }
    }
}

// ---------------------------------------------------------------------------
// attention v7: v6 (register-P via PV-aligned K-row permutation, Q in regs,
// XCD swizzle, balanced (h,b,qblk) decode) + ONE schedule change: T4
// counted-vmcnt pipeline.  v6's __syncthreads compiled to
// `s_waitcnt vmcnt(0) lgkmcnt(0); s_barrier` -- it DRAINED the glds prefetch
// issued in the same iteration, so each tile's loads had only one iteration
// of compute as slack and every L2/L3 latency tail hit the barrier with all
// 4 waves parked.  Now: 3 LDS buffers, prefetch distance 2, and the loop
// waits `vmcnt(4)` (tile-kt loads done, tile-kt+1's 4 still in flight) --
// never 0 except the last iteration.  Schedule per iter:
//   lgkmcnt(0)           (own ds_reads of buf[kt-1 mod 3] retired -> the
//                         stage below can't clobber a buffer still being read)
//   vmcnt(4|0) ; s_barrier
//   stage tile kt+2 -> buf[(kt+2)%3]   (everyone finished reading it)
//   compute buf[kt%3]
// Branches are block-uniform (nkt,kt).  sched_barrier(0) after asm waits
// (guide rule #18: hipcc hoists reg-only MFMA past asm waitcnt).
// LDS 48 KB = 3 blocks/CU (12 waves).  Math identical to v6.
// ---------------------------------------------------------------------------
__global__ __launch_bounds__(256, 3) void attention(
    const ushort* __restrict__ qkv, const int* __restrict__ length,
    float* __restrict__ out)
{
    // XCD-chunk swizzle: 1024 blocks, 8 XCDs, 128 works/XCD (bijective).
    // work layout: qblk fastest, then b, then h -> chunk = 4 (b,h) pairs
    // spanning BOTH batches (balanced) and only 2 distinct heads (L2-local).
    const int bid  = blockIdx.x;
    const int work = (bid & 7) * 128 + (bid >> 3);
    const int q0 = (work & 31) * 64;
    const int bh = work >> 5;          // 0..31
    const int b  = bh & 1;
    const int h  = bh >> 1;

    int len = length[b];
    if (len > S_) len = S_;
    if (len < 1) len = 1;
    const int nkt = (len + 63) >> 6;

    const ushort* qb = qkv + ((size_t)(b * H_ + h) * S_ + q0) * DK_;
    const ushort* kb = qkv + (size_t)M_ * D_ + (size_t)(b * H_ + h) * S_ * DK_;
    const ushort* vb = qkv + (size_t)2 * M_ * D_ + (size_t)(b * H_ + h) * DK_ * S_;

    __shared__ __align__(16) ushort Ks[3][64 * 64];    // 24 KB [key][dk], hash hK
    __shared__ __align__(16) ushort Vs[3][64 * 64];    // 24 KB [dk][key], hash r&7

    const int t = threadIdx.x, lane = t & 63, wid = t >> 6;
    const int quad = lane >> 4, l16 = lane & 15;

    // K read-side constants: krow = kbase[ct] + klocal; hK(krow) = hk (per-lane)
    const int klocal = ((l16 >> 2) << 3) + (l16 & 3);
    const int hk     = (l16 & 3) | (((l16 >> 2) & 1) << 2);

    // Q fragments: straight from global, no LDS.
    // B-operand layout: lane (quad,l16) holds Q[q=l16 of strip][(ks*4+quad)*8+j]
    short8 qfrag[2];
    {
        const ushort* qp = qb + (size_t)(wid * 16 + l16) * DK_;
        qfrag[0] = *(const short8*)(qp + quad * 8);
        qfrag[1] = *(const short8*)(qp + (4 + quad) * 8);
    }

    // stage K/V tile -> buffer buf (4 glds per wave: vmcnt ticks in 4s)
    auto stageKV = [&](int buf, int tile) {
        #pragma unroll
        for (int j = 0; j < 2; ++j) {
            const int cid = wid * 128 + j * 64 + lane;
            const int row = cid >> 3;
            const int c   = cid & 7;
            const int hKr = (row & 3) | (((row >> 3) & 1) << 2);
            glds16(kb + (size_t)(tile * 64 + row) * DK_ + (c ^ hKr) * 8,
                   &Ks[buf][cid * 8]);
            glds16(vb + (size_t)row * S_ + tile * 64 + (c ^ (row & 7)) * 8,
                   &Vs[buf][cid * 8]);
        }
    };

    // prologue: prefetch tiles 0 and 1
    stageKV(0, 0);
    if (nkt > 1) stageKV(1, 1);

    // bf16 ones fragment for the rowsum MFMA
    short8 ones8;
    #pragma unroll
    for (int i = 0; i < 8; ++i) ones8[i] = (short)0x3F80;

    float4v cacc[4] = {};
    float4v racc = {};

    int cur = 0;
    for (int kt = 0; kt < nkt; ++kt) {
        // own ds_reads retired + tile-kt loads complete; NEVER drain the
        // in-flight tile-kt+1 prefetch (counted vmcnt).  Block-uniform branch.
        if (kt == nkt - 1) {
            asm volatile("s_waitcnt vmcnt(0) lgkmcnt(0)" ::: "memory");
        } else {
            asm volatile("s_waitcnt vmcnt(4) lgkmcnt(0)" ::: "memory");
        }
        __builtin_amdgcn_sched_barrier(0);
        __builtin_amdgcn_s_barrier();
        __builtin_amdgcn_sched_barrier(0);

        // prefetch tile kt+2 into the buffer all waves just finished reading
        if (kt + 2 < nkt) {
            int sb = cur + 2; if (sb >= 3) sb -= 3;
            stageKV(sb, kt + 2);
        }

        // S^T with PV-aligned K-row permutation.  After this, lane (quad,l16)
        // holds sacc[ct][rr] = S[key=(ct>>1)*32+quad*8+(ct&1)*4+rr][q=l16].
        float4v sacc[4] = {};
        #pragma unroll
        for (int ks = 0; ks < 2; ++ks) {
            #pragma unroll
            for (int ct = 0; ct < 4; ++ct) {
                const int krow = ((ct >> 1) << 5) + ((ct & 1) << 2) + klocal;
                const int pha = (ks * 4 + quad) ^ hk;
                short8 ak = *(short8*)&Ks[cur][krow * 64 + pha * 8];
                sacc[ct] = __builtin_amdgcn_mfma_f32_16x16x32_bf16(
                    ak, qfrag[ks], sacc[ct], 0, 0, 0);
            }
        }

        // exp2 + (boundary-only) mask + truncation-pack -> PV A-frags in regs
        const bool full = ((kt + 1) * 64 <= len);
        short8 ap[2];
        #pragma unroll
        for (int ks = 0; ks < 2; ++ks) {
            union { uint u[4]; short8 s; } cv;
            #pragma unroll
            for (int hh = 0; hh < 2; ++hh) {
                const int ct = 2 * ks + hh;
                float e0 = __builtin_amdgcn_exp2f(sacc[ct][0]);
                float e1 = __builtin_amdgcn_exp2f(sacc[ct][1]);
                float e2 = __builtin_amdgcn_exp2f(sacc[ct][2]);
                float e3 = __builtin_amdgcn_exp2f(sacc[ct][3]);
                if (!full) {
                    const int kb0 = kt * 64 + ks * 32 + quad * 8 + hh * 4;
                    e0 = (kb0 + 0 < len) ? e0 : 0.f;
                    e1 = (kb0 + 1 < len) ? e1 : 0.f;
                    e2 = (kb0 + 2 < len) ? e2 : 0.f;
                    e3 = (kb0 + 3 < len) ? e3 : 0.f;
                }
                cv.u[hh * 2 + 0] = (__float_as_uint(e0) >> 16) |
                                   (__float_as_uint(e1) & 0xFFFF0000u);
                cv.u[hh * 2 + 1] = (__float_as_uint(e2) >> 16) |
                                   (__float_as_uint(e3) & 0xFFFF0000u);
            }
            ap[ks] = cv.s;
        }

        // P @ V  (+ rowsum via ones-MFMA, reusing ap).  P never touches LDS.
        #pragma unroll
        for (int ks = 0; ks < 2; ++ks) {
            #pragma unroll
            for (int ct = 0; ct < 4; ++ct) {
                const int vrow = ct * 16 + l16;
                const int phv = (ks * 4 + quad) ^ (vrow & 7);
                short8 vv = *(short8*)&Vs[cur][vrow * 64 + phv * 8];
                cacc[ct] = __builtin_amdgcn_mfma_f32_16x16x32_bf16(
                    ap[ks], vv, cacc[ct], 0, 0, 0);
            }
            racc = __builtin_amdgcn_mfma_f32_16x16x32_bf16(
                ap[ks], ones8, racc, 0, 0, 0);
        }

        cur = cur + 1; if (cur == 3) cur = 0;
    }

    // normalize + store fp32.  racc[rr] holds rowsum for q = quad*4+rr in
    // every l16 lane -- exactly where cacc[ct][rr] needs it.  No shuffles.
    #pragma unroll
    for (int rr = 0; rr < 4; ++rr) {
        const float inv = 1.0f / (racc[rr] + 1e-8f);
        const int q = q0 + wid * 16 + quad * 4 + rr;
        #pragma unroll
        for (int ct = 0; ct < 4; ++ct) {
            const int d = h * 64 + ct * 16 + l16;
            out[((size_t)b * S_ + q) * D_ + d] = cacc[ct][rr] * inv;
        }
    }
}

// ---------------------------------------------------------------------------
extern "C" void kernel_launch(void* const* d_in, const int* in_sizes, int n_in,
                              void* d_out, int out_size, void* d_ws, size_t ws_size,
                              hipStream_t stream)
{
    const float* Q   = (const float*)d_in[0];
    const int*   len = (const int*)d_in[1];
    const float* Wq  = (const float*)d_in[2];
    const float* bq  = (const float*)d_in[3];
    const float* Wk  = (const float*)d_in[4];
    const float* bk  = (const float*)d_in[5];
    const float* Wv  = (const float*)d_in[6];
    const float* bv  = (const float*)d_in[7];
    float* out = (float*)d_out;

    ushort* ws  = (ushort*)d_ws;
    ushort* Xb  = ws;                                   // 4M bf16 = 8 MB
    ushort* Wt  = ws + (size_t)M_ * D_;                 // 3M bf16 = 6 MB
    ushort* qkv = Wt + (size_t)3 * D_ * D_;             // 12M bf16 = 24 MB

    dim3 gPr(16, 16, 11);
    prep<<<gPr, 256, 0, stream>>>(Q, Wq, Wk, Wv, Xb, Wt);

    dim3 gP(M_ / 64, D_ / 128);
    proj_gemm<<<gP, 256, 0, stream>>>(Xb, Wt, bq, bk, bv, len, qkv);

    attention<<<dim3(S_ / 64 * H_ * B_), 256, 0, stream>>>(qkv, len, out);
}